// Round 2
// baseline (1393.730 us; speedup 1.0000x reference)
//
#include <hip/hip_runtime.h>
#include <hip/hip_bf16.h>

#define NN 100000     // nodes
#define NE 3200000    // edges
#define NG 512        // graphs
#define IND 128
#define H1D 32
#define H2D 16

#define BK   128              // nodes per bucket
#define NBUK 782              // ceil(NN/BK)
#define CAP  4608             // slots per bucket (mean 4096, +8 sigma)

// ---------------- workspace layout (element offsets, 4B each) ----------------
#define O_BCUR  0u            // int[1024]
#define O_GSUM  1024u         // float[512]
#define O_GCNT  1536u         // float[512]
#define O_DINV  2048u         // float[100352]
#define O_PAIRS 102400u       // int[NBUK*CAP = 3,603,456] packed: src | (localdst<<17)
#define O_H1S   3705856u      // float[NN*32]  h1s = (x@W1)*dinv  [3,200,000]
#define O_H2S   6905856u      // float[NN*16]  h2s = (feat1@W2)*dinv [1,600,000]
// total = 8,505,856 elems = 34.0 MB

__global__ __launch_bounds__(256) void k_init(int* bcur, float* gsum, float* gcnt) {
    int i = blockIdx.x * 256 + threadIdx.x;
    if (i < 1024) bcur[i] = i * CAP;
    if (i < NG) { gsum[i] = 0.f; gcnt[i] = 0.f; }
}

// Stage edges into per-bucket regions. Tile = 4096 edges per block; LDS binning
// + one bulk cursor atomic per (block,bucket) -> writes are sequential runs.
__global__ __launch_bounds__(256) void k_stage(const int* __restrict__ src,
                                               const int* __restrict__ dst,
                                               int* bcur, int* __restrict__ pairs) {
    __shared__ int cnt[NBUK], pre[NBUK], cur[NBUK], gb[NBUK];
    __shared__ int2 buf[4096];     // (packed, bucket)
    __shared__ int scan[256];
    int t = threadIdx.x;
    for (int i = t; i < NBUK; i += 256) cnt[i] = 0;
    __syncthreads();

    int eb = blockIdx.x * 4096;
    int s16[16], d16[16];
#pragma unroll
    for (int j = 0; j < 16; ++j) {
        int e = eb + j * 256 + t;
        if (e < NE) {
            s16[j] = src[e];
            d16[j] = dst[e];
            atomicAdd(&cnt[d16[j] >> 7], 1);
        } else d16[j] = -1;
    }
    __syncthreads();

    // exclusive prefix over NBUK counters (4 per thread + Hillis-Steele over 256)
    int c0 = (t * 4 + 0 < NBUK) ? cnt[t * 4 + 0] : 0;
    int c1 = (t * 4 + 1 < NBUK) ? cnt[t * 4 + 1] : 0;
    int c2 = (t * 4 + 2 < NBUK) ? cnt[t * 4 + 2] : 0;
    int c3 = (t * 4 + 3 < NBUK) ? cnt[t * 4 + 3] : 0;
    int s4 = c0 + c1 + c2 + c3;
    scan[t] = s4;
    __syncthreads();
    for (int off = 1; off < 256; off <<= 1) {
        int v = (t >= off) ? scan[t - off] : 0;
        __syncthreads();
        scan[t] += v;
        __syncthreads();
    }
    int excl = scan[t] - s4;
    if (t * 4 + 0 < NBUK) pre[t * 4 + 0] = excl;
    if (t * 4 + 1 < NBUK) pre[t * 4 + 1] = excl + c0;
    if (t * 4 + 2 < NBUK) pre[t * 4 + 2] = excl + c0 + c1;
    if (t * 4 + 3 < NBUK) pre[t * 4 + 3] = excl + c0 + c1 + c2;
    __syncthreads();

    // bulk global allocation: one atomic per nonzero bucket per block
    for (int i = t; i < NBUK; i += 256) {
        int c = cnt[i];
        gb[i] = c ? atomicAdd(&bcur[i], c) : 0;
        cur[i] = pre[i];
    }
    __syncthreads();

    // re-bin into LDS in bucket order
#pragma unroll
    for (int j = 0; j < 16; ++j) {
        if (d16[j] >= 0) {
            int b = d16[j] >> 7;
            int slot = atomicAdd(&cur[b], 1);
            buf[slot] = make_int2(s16[j] | ((d16[j] & 127) << 17), b);
        }
    }
    __syncthreads();

    // flush: consecutive slots -> consecutive global addresses (coalesced runs)
    int tot = scan[255];
    for (int slot = t; slot < tot; slot += 256) {
        int2 e = buf[slot];
        pairs[gb[e.y] + (slot - pre[e.y])] = e.x;
    }
}

// per-bucket degree histogram -> dinv; also graph node counts
__global__ __launch_bounds__(256) void k_deg(const int* __restrict__ bcur,
                                             const int* __restrict__ pairs,
                                             const int* __restrict__ batch,
                                             float* __restrict__ dinv,
                                             float* gcnt) {
    __shared__ int hist[BK];
    int t = threadIdx.x, b = blockIdx.x;
    if (t < BK) hist[t] = 0;
    __syncthreads();
    int cnt = bcur[b] - b * CAP;
    const int* pb = pairs + (size_t)b * CAP;
    for (int i = t; i < cnt; i += 256) atomicAdd(&hist[pb[i] >> 17], 1);
    __syncthreads();
    if (t < BK) {
        int d = b * BK + t;
        if (d < NN) {
            dinv[d] = rsqrtf((float)(hist[t] + 1));   // +1 self-loop
            atomicAdd(&gcnt[batch[d]], 1.0f);
        }
    }
}

// h1s = (x @ W1) * dinv : register-tiled 2 nodes x 4 k per thread
__global__ __launch_bounds__(256) void k_gemm1(const float* __restrict__ x,
                                               const float* __restrict__ W1,
                                               const float* __restrict__ dinv,
                                               float* __restrict__ h1s) {
    __shared__ float sX[64][IND + 1];   // padded: bank = (n+i)&31
    __shared__ float sW[IND * H1D];
    int t = threadIdx.x;
    int nodeBase = blockIdx.x * 64;
    for (int i = t; i < IND * H1D; i += 256) sW[i] = W1[i];
    for (int i = t; i < 64 * IND / 4; i += 256) {
        int r = i >> 5;
        int c = (i & 31) * 4;
        int d = nodeBase + r;
        float4 v = (d < NN) ? *(const float4*)&x[(size_t)d * IND + c]
                            : make_float4(0.f, 0.f, 0.f, 0.f);
        sX[r][c] = v.x; sX[r][c + 1] = v.y; sX[r][c + 2] = v.z; sX[r][c + 3] = v.w;
    }
    __syncthreads();
    int k0 = (t & 7) * 4;
    int n0 = (t >> 3) * 2;
    float a00 = 0, a01 = 0, a02 = 0, a03 = 0, a10 = 0, a11 = 0, a12 = 0, a13 = 0;
#pragma unroll 4
    for (int i = 0; i < IND; ++i) {
        float4 w = *(const float4*)&sW[i * H1D + k0];
        float x0 = sX[n0][i], x1 = sX[n0 + 1][i];
        a00 += x0 * w.x; a01 += x0 * w.y; a02 += x0 * w.z; a03 += x0 * w.w;
        a10 += x1 * w.x; a11 += x1 * w.y; a12 += x1 * w.z; a13 += x1 * w.w;
    }
    int d0 = nodeBase + n0, d1 = d0 + 1;
    if (d0 < NN) { float s = dinv[d0];
        *(float4*)&h1s[(size_t)d0 * H1D + k0] = make_float4(a00 * s, a01 * s, a02 * s, a03 * s); }
    if (d1 < NN) { float s = dinv[d1];
        *(float4*)&h1s[(size_t)d1 * H1D + k0] = make_float4(a10 * s, a11 * s, a12 * s, a13 * s); }
}

// layer-1 aggregate (LDS scatter) + bias + relu + fused gemm2 -> h2s
__global__ __launch_bounds__(256) void k_agg1(const float* __restrict__ h1s,
                                              const float* __restrict__ dinv,
                                              const int* __restrict__ bcur,
                                              const int* __restrict__ pairs,
                                              const float* __restrict__ W2,
                                              const float* __restrict__ b1,
                                              float* __restrict__ h2s) {
    __shared__ float acc[BK * H1D];   // 16 KB
    __shared__ float sW2[H1D * H2D];  // 2 KB
    int t = threadIdx.x, b = blockIdx.x;
    for (int i = t; i < BK * H1D; i += 256) acc[i] = 0.f;
    for (int i = t; i < H1D * H2D; i += 256) sW2[i] = W2[i];
    __syncthreads();
    int cnt = bcur[b] - b * CAP;
    const int* pb = pairs + (size_t)b * CAP;
    int k = t & 31, slot = t >> 5;    // 8 edge-slots x 32 feature lanes
    for (int i = slot * 4; i < cnt; i += 32) {
        int4 q = *(const int4*)&pb[i];
        int rem = cnt - i;
        { int p = q.x; float v = h1s[(size_t)(p & 0x1FFFF) * H1D + k];
          atomicAdd(&acc[(p >> 17) * H1D + k], v); }
        if (rem > 1) { int p = q.y; float v = h1s[(size_t)(p & 0x1FFFF) * H1D + k];
          atomicAdd(&acc[(p >> 17) * H1D + k], v); }
        if (rem > 2) { int p = q.z; float v = h1s[(size_t)(p & 0x1FFFF) * H1D + k];
          atomicAdd(&acc[(p >> 17) * H1D + k], v); }
        if (rem > 3) { int p = q.w; float v = h1s[(size_t)(p & 0x1FFFF) * H1D + k];
          atomicAdd(&acc[(p >> 17) * H1D + k], v); }
    }
    __syncthreads();
    int nodeBase = b * BK;
    // feat1 = relu((acc + h1s[d]) * dinv[d] + b1)  (in place in LDS)
    for (int idx = t; idx < BK * H1D; idx += 256) {
        int n = idx >> 5, kk = idx & 31;
        int d = nodeBase + n;
        if (d < NN) {
            float dv = dinv[d];
            float v = (acc[idx] + h1s[(size_t)d * H1D + kk]) * dv + b1[kk];
            acc[idx] = fmaxf(v, 0.f);
        }
    }
    __syncthreads();
    // h2s = (feat1 @ W2) * dinv
    for (int idx = t; idx < BK * H2D; idx += 256) {
        int n = idx >> 4, kk = idx & 15;
        int d = nodeBase + n;
        if (d >= NN) continue;
        const float* fr = &acc[n * H1D];
        float s = 0.f;
#pragma unroll
        for (int i2 = 0; i2 < H1D; ++i2) s += fr[i2] * sW2[i2 * H2D + kk];
        h2s[(size_t)d * H2D + kk] = s * dinv[d];
    }
}

// layer-2 aggregate + bias + relu + dot(W3) + scatter to graph sums
__global__ __launch_bounds__(256) void k_agg2(const float* __restrict__ h2s,
                                              const float* __restrict__ dinv,
                                              const int* __restrict__ bcur,
                                              const int* __restrict__ pairs,
                                              const float* __restrict__ b2,
                                              const float* __restrict__ W3,
                                              const int* __restrict__ batch,
                                              float* gsum) {
    __shared__ float acc[BK * H2D];   // 8 KB
    int t = threadIdx.x, b = blockIdx.x;
    for (int i = t; i < BK * H2D; i += 256) acc[i] = 0.f;
    __syncthreads();
    int cnt = bcur[b] - b * CAP;
    const int* pb = pairs + (size_t)b * CAP;
    int k = t & 15, slot = t >> 4;    // 16 edge-slots x 16 feature lanes
    for (int i = slot * 4; i < cnt; i += 64) {
        int4 q = *(const int4*)&pb[i];
        int rem = cnt - i;
        { int p = q.x; float v = h2s[(size_t)(p & 0x1FFFF) * H2D + k];
          atomicAdd(&acc[(p >> 17) * H2D + k], v); }
        if (rem > 1) { int p = q.y; float v = h2s[(size_t)(p & 0x1FFFF) * H2D + k];
          atomicAdd(&acc[(p >> 17) * H2D + k], v); }
        if (rem > 2) { int p = q.z; float v = h2s[(size_t)(p & 0x1FFFF) * H2D + k];
          atomicAdd(&acc[(p >> 17) * H2D + k], v); }
        if (rem > 3) { int p = q.w; float v = h2s[(size_t)(p & 0x1FFFF) * H2D + k];
          atomicAdd(&acc[(p >> 17) * H2D + k], v); }
    }
    __syncthreads();
    int nodeBase = b * BK;
    for (int idx = t; idx < BK * H2D; idx += 256) {
        int n = idx >> 4, kk = idx & 15;
        int d = nodeBase + n;
        float v = 0.f;
        if (d < NN) {
            float dv = dinv[d];
            float f = (acc[idx] + h2s[(size_t)d * H2D + kk]) * dv + b2[kk];
            v = fmaxf(f, 0.f) * W3[kk];
        }
        v += __shfl_xor(v, 1);
        v += __shfl_xor(v, 2);
        v += __shfl_xor(v, 4);
        v += __shfl_xor(v, 8);
        if (kk == 0 && d < NN) atomicAdd(&gsum[batch[d]], v);
    }
}

__global__ __launch_bounds__(256) void k_final(const float* gsum, const float* gcnt,
                                               const float* b3, float* out) {
    int g = blockIdx.x * 256 + threadIdx.x;
    if (g < NG) out[g] = gsum[g] / fmaxf(gcnt[g], 1.0f) + b3[0];
}

extern "C" void kernel_launch(void* const* d_in, const int* in_sizes, int n_in,
                              void* d_out, int out_size, void* d_ws, size_t ws_size,
                              hipStream_t stream) {
    const float* x     = (const float*)d_in[0];
    const int*   src   = (const int*)d_in[1];
    const int*   dst   = src + NE;
    const int*   batch = (const int*)d_in[2];
    const float* W1 = (const float*)d_in[3];
    const float* b1 = (const float*)d_in[4];
    const float* W2 = (const float*)d_in[5];
    const float* b2 = (const float*)d_in[6];
    const float* W3 = (const float*)d_in[7];
    const float* b3 = (const float*)d_in[8];
    float* out = (float*)d_out;

    float* ws = (float*)d_ws;
    int*   bcur  = (int*)(ws + O_BCUR);
    float* gsum  = ws + O_GSUM;
    float* gcnt  = ws + O_GCNT;
    float* dinv  = ws + O_DINV;
    int*   pairs = (int*)(ws + O_PAIRS);
    float* h1s   = ws + O_H1S;
    float* h2s   = ws + O_H2S;

    k_init <<<4, 256, 0, stream>>>(bcur, gsum, gcnt);
    k_stage<<<NBUK, 256, 0, stream>>>(src, dst, bcur, pairs);
    k_deg  <<<NBUK, 256, 0, stream>>>(bcur, pairs, batch, dinv, gcnt);
    k_gemm1<<<(NN + 63) / 64, 256, 0, stream>>>(x, W1, dinv, h1s);
    k_agg1 <<<NBUK, 256, 0, stream>>>(h1s, dinv, bcur, pairs, W2, b1, h2s);
    k_agg2 <<<NBUK, 256, 0, stream>>>(h2s, dinv, bcur, pairs, b2, W3, batch, gsum);
    k_final<<<2, 256, 0, stream>>>(gsum, gcnt, b3, out);
}

// Round 3
// 1315.119 us; speedup vs baseline: 1.0598x; 1.0598x over previous
//
#include <hip/hip_runtime.h>
#include <hip/hip_bf16.h>

#define NN 100000     // nodes
#define NE 3200000    // edges
#define NG 512        // graphs
#define IND 128
#define H1D 32
#define H2D 16

#define BK   128              // nodes per bucket
#define NBUK 782              // ceil(NN/BK)
#define CAP  4672             // slots per bucket (mean 4096; ~+9 sigma + prefetch slack)
#define DUMMY NN              // dummy src row (zeroed); localdst bits = 0

// ---------------- workspace layout (element offsets, 4B each) ----------------
#define O_BCUR  0u            // int[1024]
#define O_GSUM  1024u         // float[512]
#define O_GCNT  1536u         // float[512]
#define O_DINV  2048u         // float[100352]
#define O_PAIRS 102400u       // int[NBUK*CAP = 3,653,504] packed: src | (localdst<<17)
#define O_H1S   3755904u      // float[(NN+1)*32]  h1s = (x@W1)*dinv, +1 dummy row
#define O_H2S   6955936u      // float[(NN+1)*16]  h2s = (feat1@W2)*dinv, +1 dummy row
// total = 8,555,952 elems = 34.2 MB

__global__ __launch_bounds__(256) void k_init(int* bcur, float* gsum, float* gcnt,
                                              float* h1s, float* h2s) {
    int i = blockIdx.x * 256 + threadIdx.x;
    if (i < 1024) bcur[i] = i * CAP;
    if (i < NG) { gsum[i] = 0.f; gcnt[i] = 0.f; }
    if (i < H1D) h1s[(size_t)NN * H1D + i] = 0.f;   // dummy row for padded edges
    if (i < H2D) h2s[(size_t)NN * H2D + i] = 0.f;
}

// Stage edges into per-bucket regions. Tile = 4096 edges per block; LDS binning
// + one bulk cursor atomic per (block,bucket) -> writes are sequential runs.
__global__ __launch_bounds__(256) void k_stage(const int* __restrict__ src,
                                               const int* __restrict__ dst,
                                               int* bcur, int* __restrict__ pairs) {
    __shared__ int cnt[NBUK], pre[NBUK], cur[NBUK], gb[NBUK];
    __shared__ int2 buf[4096];     // (packed, bucket)
    __shared__ int scan[256];
    int t = threadIdx.x;
    for (int i = t; i < NBUK; i += 256) cnt[i] = 0;
    __syncthreads();

    int eb = blockIdx.x * 4096;
    int s16[16], d16[16];
#pragma unroll
    for (int j = 0; j < 16; ++j) {
        int e = eb + j * 256 + t;
        if (e < NE) {
            s16[j] = src[e];
            d16[j] = dst[e];
            atomicAdd(&cnt[d16[j] >> 7], 1);
        } else d16[j] = -1;
    }
    __syncthreads();

    // exclusive prefix over NBUK counters (4 per thread + Hillis-Steele over 256)
    int c0 = (t * 4 + 0 < NBUK) ? cnt[t * 4 + 0] : 0;
    int c1 = (t * 4 + 1 < NBUK) ? cnt[t * 4 + 1] : 0;
    int c2 = (t * 4 + 2 < NBUK) ? cnt[t * 4 + 2] : 0;
    int c3 = (t * 4 + 3 < NBUK) ? cnt[t * 4 + 3] : 0;
    int s4 = c0 + c1 + c2 + c3;
    scan[t] = s4;
    __syncthreads();
    for (int off = 1; off < 256; off <<= 1) {
        int v = (t >= off) ? scan[t - off] : 0;
        __syncthreads();
        scan[t] += v;
        __syncthreads();
    }
    int excl = scan[t] - s4;
    if (t * 4 + 0 < NBUK) pre[t * 4 + 0] = excl;
    if (t * 4 + 1 < NBUK) pre[t * 4 + 1] = excl + c0;
    if (t * 4 + 2 < NBUK) pre[t * 4 + 2] = excl + c0 + c1;
    if (t * 4 + 3 < NBUK) pre[t * 4 + 3] = excl + c0 + c1 + c2;
    __syncthreads();

    // bulk global allocation: one atomic per nonzero bucket per block
    for (int i = t; i < NBUK; i += 256) {
        int c = cnt[i];
        gb[i] = c ? atomicAdd(&bcur[i], c) : 0;
        cur[i] = pre[i];
    }
    __syncthreads();

    // re-bin into LDS in bucket order
#pragma unroll
    for (int j = 0; j < 16; ++j) {
        if (d16[j] >= 0) {
            int b = d16[j] >> 7;
            int slot = atomicAdd(&cur[b], 1);
            buf[slot] = make_int2(s16[j] | ((d16[j] & 127) << 17), b);
        }
    }
    __syncthreads();

    // flush: consecutive slots -> consecutive global addresses (coalesced runs)
    int tot = scan[255];
    for (int slot = t; slot < tot; slot += 256) {
        int2 e = buf[slot];
        pairs[gb[e.y] + (slot - pre[e.y])] = e.x;
    }
}

// per-bucket degree histogram -> dinv; graph node counts; pad bucket to mult-of-8
__global__ __launch_bounds__(256) void k_deg(const int* __restrict__ bcur,
                                             int* __restrict__ pairs,
                                             const int* __restrict__ batch,
                                             float* __restrict__ dinv,
                                             float* gcnt) {
    __shared__ int hist[BK];
    int t = threadIdx.x, b = blockIdx.x;
    if (t < BK) hist[t] = 0;
    __syncthreads();
    int cnt = bcur[b] - b * CAP;
    int cnt_pad = (cnt + 7) & ~7;
    if (t < cnt_pad - cnt) pairs[(size_t)b * CAP + cnt + t] = DUMMY;  // pad slots
    const int* pb = pairs + (size_t)b * CAP;
    for (int i = t; i < cnt; i += 256) atomicAdd(&hist[pb[i] >> 17], 1);
    __syncthreads();
    if (t < BK) {
        int d = b * BK + t;
        if (d < NN) {
            dinv[d] = rsqrtf((float)(hist[t] + 1));   // +1 self-loop
            atomicAdd(&gcnt[batch[d]], 1.0f);
        }
    }
}

// h1s = (x @ W1) * dinv : register-tiled 2 nodes x 4 k per thread
__global__ __launch_bounds__(256) void k_gemm1(const float* __restrict__ x,
                                               const float* __restrict__ W1,
                                               const float* __restrict__ dinv,
                                               float* __restrict__ h1s) {
    __shared__ float sX[64][IND + 1];
    __shared__ float sW[IND * H1D];
    int t = threadIdx.x;
    int nodeBase = blockIdx.x * 64;
    for (int i = t; i < IND * H1D; i += 256) sW[i] = W1[i];
    for (int i = t; i < 64 * IND / 4; i += 256) {
        int r = i >> 5;
        int c = (i & 31) * 4;
        int d = nodeBase + r;
        float4 v = (d < NN) ? *(const float4*)&x[(size_t)d * IND + c]
                            : make_float4(0.f, 0.f, 0.f, 0.f);
        sX[r][c] = v.x; sX[r][c + 1] = v.y; sX[r][c + 2] = v.z; sX[r][c + 3] = v.w;
    }
    __syncthreads();
    int k0 = (t & 7) * 4;
    int n0 = (t >> 3) * 2;
    float a00 = 0, a01 = 0, a02 = 0, a03 = 0, a10 = 0, a11 = 0, a12 = 0, a13 = 0;
#pragma unroll 4
    for (int i = 0; i < IND; ++i) {
        float4 w = *(const float4*)&sW[i * H1D + k0];
        float x0 = sX[n0][i], x1 = sX[n0 + 1][i];
        a00 += x0 * w.x; a01 += x0 * w.y; a02 += x0 * w.z; a03 += x0 * w.w;
        a10 += x1 * w.x; a11 += x1 * w.y; a12 += x1 * w.z; a13 += x1 * w.w;
    }
    int d0 = nodeBase + n0, d1 = d0 + 1;
    if (d0 < NN) { float s = dinv[d0];
        *(float4*)&h1s[(size_t)d0 * H1D + k0] = make_float4(a00 * s, a01 * s, a02 * s, a03 * s); }
    if (d1 < NN) { float s = dinv[d1];
        *(float4*)&h1s[(size_t)d1 * H1D + k0] = make_float4(a10 * s, a11 * s, a12 * s, a13 * s); }
}

// layer-1 aggregate (LDS scatter, branch-free 8-deep gather pipeline)
// + bias + relu + fused gemm2 -> h2s
__global__ __launch_bounds__(256) void k_agg1(const float* __restrict__ h1s,
                                              const float* __restrict__ dinv,
                                              const int* __restrict__ bcur,
                                              const int* __restrict__ pairs,
                                              const float* __restrict__ W2,
                                              const float* __restrict__ b1,
                                              float* __restrict__ h2s) {
    __shared__ float acc[BK * H1D];   // 16 KB
    __shared__ float sW2[H1D * H2D];  // 2 KB
    int t = threadIdx.x, b = blockIdx.x;
    for (int i = t; i < BK * H1D; i += 256) acc[i] = 0.f;
    for (int i = t; i < H1D * H2D; i += 256) sW2[i] = W2[i];
    __syncthreads();
    int cnt = bcur[b] - b * CAP;
    int cnt_pad = (cnt + 7) & ~7;
    const int* pb = pairs + (size_t)b * CAP;
    int k = t & 31, slot = t >> 5;    // 8 groups x 32 feature lanes, 8 edges/group/iter
    int i = slot * 8;
    int4 q0, q1;
    if (i < cnt_pad) { q0 = *(const int4*)&pb[i]; q1 = *(const int4*)&pb[i + 4]; }
    while (i < cnt_pad) {
        // unconditional prefetch (slack: i+71 <= cnt_pad+63 < CAP, garbage unused)
        int4 n0 = *(const int4*)&pb[i + 64];
        int4 n1 = *(const int4*)&pb[i + 68];
        float v0 = h1s[(size_t)(q0.x & 0x1FFFF) * H1D + k];
        float v1 = h1s[(size_t)(q0.y & 0x1FFFF) * H1D + k];
        float v2 = h1s[(size_t)(q0.z & 0x1FFFF) * H1D + k];
        float v3 = h1s[(size_t)(q0.w & 0x1FFFF) * H1D + k];
        float v4 = h1s[(size_t)(q1.x & 0x1FFFF) * H1D + k];
        float v5 = h1s[(size_t)(q1.y & 0x1FFFF) * H1D + k];
        float v6 = h1s[(size_t)(q1.z & 0x1FFFF) * H1D + k];
        float v7 = h1s[(size_t)(q1.w & 0x1FFFF) * H1D + k];
        atomicAdd(&acc[(q0.x >> 17) * H1D + k], v0);
        atomicAdd(&acc[(q0.y >> 17) * H1D + k], v1);
        atomicAdd(&acc[(q0.z >> 17) * H1D + k], v2);
        atomicAdd(&acc[(q0.w >> 17) * H1D + k], v3);
        atomicAdd(&acc[(q1.x >> 17) * H1D + k], v4);
        atomicAdd(&acc[(q1.y >> 17) * H1D + k], v5);
        atomicAdd(&acc[(q1.z >> 17) * H1D + k], v6);
        atomicAdd(&acc[(q1.w >> 17) * H1D + k], v7);
        q0 = n0; q1 = n1;
        i += 64;
    }
    __syncthreads();
    int nodeBase = b * BK;
    // feat1 = relu((acc + h1s[d]) * dinv[d] + b1)  (in place in LDS)
    for (int idx = t; idx < BK * H1D; idx += 256) {
        int n = idx >> 5, kk = idx & 31;
        int d = nodeBase + n;
        if (d < NN) {
            float dv = dinv[d];
            float v = (acc[idx] + h1s[(size_t)d * H1D + kk]) * dv + b1[kk];
            acc[idx] = fmaxf(v, 0.f);
        }
    }
    __syncthreads();
    // h2s = (feat1 @ W2) * dinv
    for (int idx = t; idx < BK * H2D; idx += 256) {
        int n = idx >> 4, kk = idx & 15;
        int d = nodeBase + n;
        if (d >= NN) continue;
        const float* fr = &acc[n * H1D];
        float s = 0.f;
#pragma unroll
        for (int i2 = 0; i2 < H1D; ++i2) s += fr[i2] * sW2[i2 * H2D + kk];
        h2s[(size_t)d * H2D + kk] = s * dinv[d];
    }
}

// layer-2 aggregate (branch-free 8-deep pipeline) + bias + relu + dot(W3) + scatter
__global__ __launch_bounds__(256) void k_agg2(const float* __restrict__ h2s,
                                              const float* __restrict__ dinv,
                                              const int* __restrict__ bcur,
                                              const int* __restrict__ pairs,
                                              const float* __restrict__ b2,
                                              const float* __restrict__ W3,
                                              const int* __restrict__ batch,
                                              float* gsum) {
    __shared__ float acc[BK * H2D];   // 8 KB
    int t = threadIdx.x, b = blockIdx.x;
    for (int i = t; i < BK * H2D; i += 256) acc[i] = 0.f;
    __syncthreads();
    int cnt = bcur[b] - b * CAP;
    int cnt_pad = (cnt + 7) & ~7;
    const int* pb = pairs + (size_t)b * CAP;
    int k = t & 15, slot = t >> 4;    // 16 groups x 16 feature lanes, 8 edges/group/iter
    int i = slot * 8;
    int4 q0, q1;
    if (i < cnt_pad) { q0 = *(const int4*)&pb[i]; q1 = *(const int4*)&pb[i + 4]; }
    while (i < cnt_pad) {
        int4 n0 = *(const int4*)&pb[i + 128];
        int4 n1 = *(const int4*)&pb[i + 132];
        float v0 = h2s[(size_t)(q0.x & 0x1FFFF) * H2D + k];
        float v1 = h2s[(size_t)(q0.y & 0x1FFFF) * H2D + k];
        float v2 = h2s[(size_t)(q0.z & 0x1FFFF) * H2D + k];
        float v3 = h2s[(size_t)(q0.w & 0x1FFFF) * H2D + k];
        float v4 = h2s[(size_t)(q1.x & 0x1FFFF) * H2D + k];
        float v5 = h2s[(size_t)(q1.y & 0x1FFFF) * H2D + k];
        float v6 = h2s[(size_t)(q1.z & 0x1FFFF) * H2D + k];
        float v7 = h2s[(size_t)(q1.w & 0x1FFFF) * H2D + k];
        atomicAdd(&acc[(q0.x >> 17) * H2D + k], v0);
        atomicAdd(&acc[(q0.y >> 17) * H2D + k], v1);
        atomicAdd(&acc[(q0.z >> 17) * H2D + k], v2);
        atomicAdd(&acc[(q0.w >> 17) * H2D + k], v3);
        atomicAdd(&acc[(q1.x >> 17) * H2D + k], v4);
        atomicAdd(&acc[(q1.y >> 17) * H2D + k], v5);
        atomicAdd(&acc[(q1.z >> 17) * H2D + k], v6);
        atomicAdd(&acc[(q1.w >> 17) * H2D + k], v7);
        q0 = n0; q1 = n1;
        i += 128;
    }
    __syncthreads();
    int nodeBase = b * BK;
    for (int idx = t; idx < BK * H2D; idx += 256) {
        int n = idx >> 4, kk = idx & 15;
        int d = nodeBase + n;
        float v = 0.f;
        if (d < NN) {
            float dv = dinv[d];
            float f = (acc[idx] + h2s[(size_t)d * H2D + kk]) * dv + b2[kk];
            v = fmaxf(f, 0.f) * W3[kk];
        }
        v += __shfl_xor(v, 1);
        v += __shfl_xor(v, 2);
        v += __shfl_xor(v, 4);
        v += __shfl_xor(v, 8);
        if (kk == 0 && d < NN) atomicAdd(&gsum[batch[d]], v);
    }
}

__global__ __launch_bounds__(256) void k_final(const float* gsum, const float* gcnt,
                                               const float* b3, float* out) {
    int g = blockIdx.x * 256 + threadIdx.x;
    if (g < NG) out[g] = gsum[g] / fmaxf(gcnt[g], 1.0f) + b3[0];
}

extern "C" void kernel_launch(void* const* d_in, const int* in_sizes, int n_in,
                              void* d_out, int out_size, void* d_ws, size_t ws_size,
                              hipStream_t stream) {
    const float* x     = (const float*)d_in[0];
    const int*   src   = (const int*)d_in[1];
    const int*   dst   = src + NE;
    const int*   batch = (const int*)d_in[2];
    const float* W1 = (const float*)d_in[3];
    const float* b1 = (const float*)d_in[4];
    const float* W2 = (const float*)d_in[5];
    const float* b2 = (const float*)d_in[6];
    const float* W3 = (const float*)d_in[7];
    const float* b3 = (const float*)d_in[8];
    float* out = (float*)d_out;

    float* ws = (float*)d_ws;
    int*   bcur  = (int*)(ws + O_BCUR);
    float* gsum  = ws + O_GSUM;
    float* gcnt  = ws + O_GCNT;
    float* dinv  = ws + O_DINV;
    int*   pairs = (int*)(ws + O_PAIRS);
    float* h1s   = ws + O_H1S;
    float* h2s   = ws + O_H2S;

    k_init <<<4, 256, 0, stream>>>(bcur, gsum, gcnt, h1s, h2s);
    k_stage<<<NBUK, 256, 0, stream>>>(src, dst, bcur, pairs);
    k_deg  <<<NBUK, 256, 0, stream>>>(bcur, pairs, batch, dinv, gcnt);
    k_gemm1<<<(NN + 63) / 64, 256, 0, stream>>>(x, W1, dinv, h1s);
    k_agg1 <<<NBUK, 256, 0, stream>>>(h1s, dinv, bcur, pairs, W2, b1, h2s);
    k_agg2 <<<NBUK, 256, 0, stream>>>(h2s, dinv, bcur, pairs, b2, W3, batch, gsum);
    k_final<<<2, 256, 0, stream>>>(gsum, gcnt, b3, out);
}

// Round 4
// 1311.544 us; speedup vs baseline: 1.0627x; 1.0027x over previous
//
#include <hip/hip_runtime.h>
#include <hip/hip_bf16.h>

#define NN 100000     // nodes
#define NE 3200000    // edges
#define NG 512        // graphs
#define IND 128
#define H1D 32
#define H2D 16

#define BK   128              // nodes per bucket
#define NBUK 782              // ceil(NN/BK)
#define CAP  4672             // slots per bucket (mean 4096; ~+9 sigma + prefetch slack)
#define DUMMY NN              // dummy src row (zeroed); localdst bits = 0
#define S1 33                 // padded LDS stride for H1D rows
#define S2 17                 // padded LDS stride for H2D rows

// ---------------- workspace layout (element offsets, 4B each) ----------------
#define O_BCUR  0u            // int[1024]
#define O_GSUM  1024u         // float[512]
#define O_GCNT  1536u         // float[512]
#define O_DINV  2048u         // float[100352]
#define O_PAIRS 102400u       // int[NBUK*CAP = 3,653,504] packed: src | (localdst<<17)
#define O_H1S   3755904u      // float[(NN+1)*32]  h1s = (x@W1)*dinv, +1 dummy row
#define O_H2S   6955936u      // float[(NN+1)*16]  h2s = (feat1@W2)*dinv, +1 dummy row

__global__ __launch_bounds__(256) void k_init(int* bcur, float* gsum, float* gcnt,
                                              float* h1s, float* h2s) {
    int i = blockIdx.x * 256 + threadIdx.x;
    if (i < 1024) bcur[i] = i * CAP;
    if (i < NG) { gsum[i] = 0.f; gcnt[i] = 0.f; }
    if (i < H1D) h1s[(size_t)NN * H1D + i] = 0.f;   // dummy row for padded edges
    if (i < H2D) h2s[(size_t)NN * H2D + i] = 0.f;
}

// Stage edges into per-bucket regions. Tile = 4096 edges per block; LDS binning
// + one bulk cursor atomic per (block,bucket) -> writes are sequential runs.
__global__ __launch_bounds__(256) void k_stage(const int* __restrict__ src,
                                               const int* __restrict__ dst,
                                               int* bcur, int* __restrict__ pairs) {
    __shared__ int cnt[NBUK], pre[NBUK], cur[NBUK], gb[NBUK];
    __shared__ int2 buf[4096];     // (packed, bucket)
    __shared__ int scan[256];
    int t = threadIdx.x;
    for (int i = t; i < NBUK; i += 256) cnt[i] = 0;
    __syncthreads();

    int eb = blockIdx.x * 4096;
    int s16[16], d16[16];
#pragma unroll
    for (int j = 0; j < 16; ++j) {
        int e = eb + j * 256 + t;
        if (e < NE) {
            s16[j] = src[e];
            d16[j] = dst[e];
            atomicAdd(&cnt[d16[j] >> 7], 1);
        } else d16[j] = -1;
    }
    __syncthreads();

    int c0 = (t * 4 + 0 < NBUK) ? cnt[t * 4 + 0] : 0;
    int c1 = (t * 4 + 1 < NBUK) ? cnt[t * 4 + 1] : 0;
    int c2 = (t * 4 + 2 < NBUK) ? cnt[t * 4 + 2] : 0;
    int c3 = (t * 4 + 3 < NBUK) ? cnt[t * 4 + 3] : 0;
    int s4 = c0 + c1 + c2 + c3;
    scan[t] = s4;
    __syncthreads();
    for (int off = 1; off < 256; off <<= 1) {
        int v = (t >= off) ? scan[t - off] : 0;
        __syncthreads();
        scan[t] += v;
        __syncthreads();
    }
    int excl = scan[t] - s4;
    if (t * 4 + 0 < NBUK) pre[t * 4 + 0] = excl;
    if (t * 4 + 1 < NBUK) pre[t * 4 + 1] = excl + c0;
    if (t * 4 + 2 < NBUK) pre[t * 4 + 2] = excl + c0 + c1;
    if (t * 4 + 3 < NBUK) pre[t * 4 + 3] = excl + c0 + c1 + c2;
    __syncthreads();

    for (int i = t; i < NBUK; i += 256) {
        int c = cnt[i];
        gb[i] = c ? atomicAdd(&bcur[i], c) : 0;
        cur[i] = pre[i];
    }
    __syncthreads();

#pragma unroll
    for (int j = 0; j < 16; ++j) {
        if (d16[j] >= 0) {
            int b = d16[j] >> 7;
            int slot = atomicAdd(&cur[b], 1);
            buf[slot] = make_int2(s16[j] | ((d16[j] & 127) << 17), b);
        }
    }
    __syncthreads();

    int tot = scan[255];
    for (int slot = t; slot < tot; slot += 256) {
        int2 e = buf[slot];
        pairs[gb[e.y] + (slot - pre[e.y])] = e.x;
    }
}

// per-bucket degree histogram -> dinv; graph node counts; pad bucket to mult-of-8
__global__ __launch_bounds__(256) void k_deg(const int* __restrict__ bcur,
                                             int* __restrict__ pairs,
                                             const int* __restrict__ batch,
                                             float* __restrict__ dinv,
                                             float* gcnt) {
    __shared__ int hist[BK];
    int t = threadIdx.x, b = blockIdx.x;
    if (t < BK) hist[t] = 0;
    __syncthreads();
    int cnt = bcur[b] - b * CAP;
    int cnt_pad = (cnt + 7) & ~7;
    if (t < cnt_pad - cnt) pairs[(size_t)b * CAP + cnt + t] = DUMMY;  // pad slots
    const int* pb = pairs + (size_t)b * CAP;
    for (int i = t; i < cnt; i += 256) atomicAdd(&hist[pb[i] >> 17], 1);
    __syncthreads();
    if (t < BK) {
        int d = b * BK + t;
        if (d < NN) {
            dinv[d] = rsqrtf((float)(hist[t] + 1));   // +1 self-loop
            atomicAdd(&gcnt[batch[d]], 1.0f);
        }
    }
}

// h1s = (x @ W1) * dinv : register-tiled 2 nodes x 4 k per thread
__global__ __launch_bounds__(256) void k_gemm1(const float* __restrict__ x,
                                               const float* __restrict__ W1,
                                               const float* __restrict__ dinv,
                                               float* __restrict__ h1s) {
    __shared__ float sX[64][IND + 1];
    __shared__ float sW[IND * H1D];
    int t = threadIdx.x;
    int nodeBase = blockIdx.x * 64;
    for (int i = t; i < IND * H1D; i += 256) sW[i] = W1[i];
    for (int i = t; i < 64 * IND / 4; i += 256) {
        int r = i >> 5;
        int c = (i & 31) * 4;
        int d = nodeBase + r;
        float4 v = (d < NN) ? *(const float4*)&x[(size_t)d * IND + c]
                            : make_float4(0.f, 0.f, 0.f, 0.f);
        sX[r][c] = v.x; sX[r][c + 1] = v.y; sX[r][c + 2] = v.z; sX[r][c + 3] = v.w;
    }
    __syncthreads();
    int k0 = (t & 7) * 4;
    int n0 = (t >> 3) * 2;
    float a00 = 0, a01 = 0, a02 = 0, a03 = 0, a10 = 0, a11 = 0, a12 = 0, a13 = 0;
#pragma unroll 4
    for (int i = 0; i < IND; ++i) {
        float4 w = *(const float4*)&sW[i * H1D + k0];
        float x0 = sX[n0][i], x1 = sX[n0 + 1][i];
        a00 += x0 * w.x; a01 += x0 * w.y; a02 += x0 * w.z; a03 += x0 * w.w;
        a10 += x1 * w.x; a11 += x1 * w.y; a12 += x1 * w.z; a13 += x1 * w.w;
    }
    int d0 = nodeBase + n0, d1 = d0 + 1;
    if (d0 < NN) { float s = dinv[d0];
        *(float4*)&h1s[(size_t)d0 * H1D + k0] = make_float4(a00 * s, a01 * s, a02 * s, a03 * s); }
    if (d1 < NN) { float s = dinv[d1];
        *(float4*)&h1s[(size_t)d1 * H1D + k0] = make_float4(a10 * s, a11 * s, a12 * s, a13 * s); }
}

// layer-1 aggregate: 8-lane groups, float4 gathers, 8 independent edges per
// iteration kept in a register batch (forces >=8 lines in flight per group).
__global__ __launch_bounds__(256, 3) void k_agg1(const float* __restrict__ h1s,
                                                 const float* __restrict__ dinv,
                                                 const int* __restrict__ bcur,
                                                 const int* __restrict__ pairs,
                                                 const float* __restrict__ W2,
                                                 const float* __restrict__ b1,
                                                 float* __restrict__ h2s) {
    __shared__ float acc[BK * S1];    // 16.9 KB, padded stride
    __shared__ float sW2[H1D * H2D];  // 2 KB
    int t = threadIdx.x, b = blockIdx.x;
    for (int i = t; i < BK * S1; i += 256) acc[i] = 0.f;
    for (int i = t; i < H1D * H2D; i += 256) sW2[i] = W2[i];
    __syncthreads();
    int cnt = bcur[b] - b * CAP;
    int cnt_pad = (cnt + 7) & ~7;
    const int* pb = pairs + (size_t)b * CAP;
    const float4* h1s4 = (const float4*)h1s;
    int k4 = t & 7;       // float4 index within 32-float row
    int g  = t >> 3;      // group 0..31; 8 edges per group per iter; stride 256
    int i = g * 8;
    int4 q0, q1;
    if (i < cnt_pad) { q0 = *(const int4*)&pb[i]; q1 = *(const int4*)&pb[i + 4]; }
    while (i < cnt_pad) {
        int4 p0 = q0, p1 = q1;
        // unconditional prefetch; over-read stays inside d_ws, never dereferenced
        q0 = *(const int4*)&pb[i + 256];
        q1 = *(const int4*)&pb[i + 260];
        float4 r0 = h1s4[(size_t)(p0.x & 0x1FFFF) * 8 + k4];
        float4 r1 = h1s4[(size_t)(p0.y & 0x1FFFF) * 8 + k4];
        float4 r2 = h1s4[(size_t)(p0.z & 0x1FFFF) * 8 + k4];
        float4 r3 = h1s4[(size_t)(p0.w & 0x1FFFF) * 8 + k4];
        float4 r4 = h1s4[(size_t)(p1.x & 0x1FFFF) * 8 + k4];
        float4 r5 = h1s4[(size_t)(p1.y & 0x1FFFF) * 8 + k4];
        float4 r6 = h1s4[(size_t)(p1.z & 0x1FFFF) * 8 + k4];
        float4 r7 = h1s4[(size_t)(p1.w & 0x1FFFF) * 8 + k4];
        int c = k4 * 4;
        float* a0 = &acc[(p0.x >> 17) * S1 + c];
        float* a1 = &acc[(p0.y >> 17) * S1 + c];
        float* a2 = &acc[(p0.z >> 17) * S1 + c];
        float* a3 = &acc[(p0.w >> 17) * S1 + c];
        float* a4 = &acc[(p1.x >> 17) * S1 + c];
        float* a5 = &acc[(p1.y >> 17) * S1 + c];
        float* a6 = &acc[(p1.z >> 17) * S1 + c];
        float* a7 = &acc[(p1.w >> 17) * S1 + c];
        atomicAdd(a0 + 0, r0.x); atomicAdd(a0 + 1, r0.y); atomicAdd(a0 + 2, r0.z); atomicAdd(a0 + 3, r0.w);
        atomicAdd(a1 + 0, r1.x); atomicAdd(a1 + 1, r1.y); atomicAdd(a1 + 2, r1.z); atomicAdd(a1 + 3, r1.w);
        atomicAdd(a2 + 0, r2.x); atomicAdd(a2 + 1, r2.y); atomicAdd(a2 + 2, r2.z); atomicAdd(a2 + 3, r2.w);
        atomicAdd(a3 + 0, r3.x); atomicAdd(a3 + 1, r3.y); atomicAdd(a3 + 2, r3.z); atomicAdd(a3 + 3, r3.w);
        atomicAdd(a4 + 0, r4.x); atomicAdd(a4 + 1, r4.y); atomicAdd(a4 + 2, r4.z); atomicAdd(a4 + 3, r4.w);
        atomicAdd(a5 + 0, r5.x); atomicAdd(a5 + 1, r5.y); atomicAdd(a5 + 2, r5.z); atomicAdd(a5 + 3, r5.w);
        atomicAdd(a6 + 0, r6.x); atomicAdd(a6 + 1, r6.y); atomicAdd(a6 + 2, r6.z); atomicAdd(a6 + 3, r6.w);
        atomicAdd(a7 + 0, r7.x); atomicAdd(a7 + 1, r7.y); atomicAdd(a7 + 2, r7.z); atomicAdd(a7 + 3, r7.w);
        i += 256;
    }
    __syncthreads();
    int nodeBase = b * BK;
    // feat1 = relu((acc + h1s[d]) * dinv[d] + b1)  (in place in LDS)
    for (int idx = t; idx < BK * H1D; idx += 256) {
        int n = idx >> 5, kk = idx & 31;
        int d = nodeBase + n;
        if (d < NN) {
            float dv = dinv[d];
            float v = (acc[n * S1 + kk] + h1s[(size_t)d * H1D + kk]) * dv + b1[kk];
            acc[n * S1 + kk] = fmaxf(v, 0.f);
        }
    }
    __syncthreads();
    // h2s = (feat1 @ W2) * dinv
    for (int idx = t; idx < BK * H2D; idx += 256) {
        int n = idx >> 4, kk = idx & 15;
        int d = nodeBase + n;
        if (d >= NN) continue;
        const float* fr = &acc[n * S1];
        float s = 0.f;
#pragma unroll
        for (int i2 = 0; i2 < H1D; ++i2) s += fr[i2] * sW2[i2 * H2D + kk];
        h2s[(size_t)d * H2D + kk] = s * dinv[d];
    }
}

// layer-2 aggregate: 4-lane groups, float4 gathers, 8-edge register batch
// + bias + relu + dot(W3) + scatter to graph sums
__global__ __launch_bounds__(256, 3) void k_agg2(const float* __restrict__ h2s,
                                                 const float* __restrict__ dinv,
                                                 const int* __restrict__ bcur,
                                                 const int* __restrict__ pairs,
                                                 const float* __restrict__ b2,
                                                 const float* __restrict__ W3,
                                                 const int* __restrict__ batch,
                                                 float* gsum) {
    __shared__ float acc[BK * S2];   // 8.7 KB, padded stride
    int t = threadIdx.x, b = blockIdx.x;
    for (int i = t; i < BK * S2; i += 256) acc[i] = 0.f;
    __syncthreads();
    int cnt = bcur[b] - b * CAP;
    int cnt_pad = (cnt + 7) & ~7;
    const int* pb = pairs + (size_t)b * CAP;
    const float4* h2s4 = (const float4*)h2s;
    int k4 = t & 3;       // float4 index within 16-float row
    int g  = t >> 2;      // group 0..63; 8 edges per group per iter; stride 512
    int i = g * 8;
    int4 q0, q1;
    if (i < cnt_pad) { q0 = *(const int4*)&pb[i]; q1 = *(const int4*)&pb[i + 4]; }
    while (i < cnt_pad) {
        int4 p0 = q0, p1 = q1;
        q0 = *(const int4*)&pb[i + 512];
        q1 = *(const int4*)&pb[i + 516];
        float4 r0 = h2s4[(size_t)(p0.x & 0x1FFFF) * 4 + k4];
        float4 r1 = h2s4[(size_t)(p0.y & 0x1FFFF) * 4 + k4];
        float4 r2 = h2s4[(size_t)(p0.z & 0x1FFFF) * 4 + k4];
        float4 r3 = h2s4[(size_t)(p0.w & 0x1FFFF) * 4 + k4];
        float4 r4 = h2s4[(size_t)(p1.x & 0x1FFFF) * 4 + k4];
        float4 r5 = h2s4[(size_t)(p1.y & 0x1FFFF) * 4 + k4];
        float4 r6 = h2s4[(size_t)(p1.z & 0x1FFFF) * 4 + k4];
        float4 r7 = h2s4[(size_t)(p1.w & 0x1FFFF) * 4 + k4];
        int c = k4 * 4;
        float* a0 = &acc[(p0.x >> 17) * S2 + c];
        float* a1 = &acc[(p0.y >> 17) * S2 + c];
        float* a2 = &acc[(p0.z >> 17) * S2 + c];
        float* a3 = &acc[(p0.w >> 17) * S2 + c];
        float* a4 = &acc[(p1.x >> 17) * S2 + c];
        float* a5 = &acc[(p1.y >> 17) * S2 + c];
        float* a6 = &acc[(p1.z >> 17) * S2 + c];
        float* a7 = &acc[(p1.w >> 17) * S2 + c];
        atomicAdd(a0 + 0, r0.x); atomicAdd(a0 + 1, r0.y); atomicAdd(a0 + 2, r0.z); atomicAdd(a0 + 3, r0.w);
        atomicAdd(a1 + 0, r1.x); atomicAdd(a1 + 1, r1.y); atomicAdd(a1 + 2, r1.z); atomicAdd(a1 + 3, r1.w);
        atomicAdd(a2 + 0, r2.x); atomicAdd(a2 + 1, r2.y); atomicAdd(a2 + 2, r2.z); atomicAdd(a2 + 3, r2.w);
        atomicAdd(a3 + 0, r3.x); atomicAdd(a3 + 1, r3.y); atomicAdd(a3 + 2, r3.z); atomicAdd(a3 + 3, r3.w);
        atomicAdd(a4 + 0, r4.x); atomicAdd(a4 + 1, r4.y); atomicAdd(a4 + 2, r4.z); atomicAdd(a4 + 3, r4.w);
        atomicAdd(a5 + 0, r5.x); atomicAdd(a5 + 1, r5.y); atomicAdd(a5 + 2, r5.z); atomicAdd(a5 + 3, r5.w);
        atomicAdd(a6 + 0, r6.x); atomicAdd(a6 + 1, r6.y); atomicAdd(a6 + 2, r6.z); atomicAdd(a6 + 3, r6.w);
        atomicAdd(a7 + 0, r7.x); atomicAdd(a7 + 1, r7.y); atomicAdd(a7 + 2, r7.z); atomicAdd(a7 + 3, r7.w);
        i += 512;
    }
    __syncthreads();
    int nodeBase = b * BK;
    for (int idx = t; idx < BK * H2D; idx += 256) {
        int n = idx >> 4, kk = idx & 15;
        int d = nodeBase + n;
        float v = 0.f;
        if (d < NN) {
            float dv = dinv[d];
            float f = (acc[n * S2 + kk] + h2s[(size_t)d * H2D + kk]) * dv + b2[kk];
            v = fmaxf(f, 0.f) * W3[kk];
        }
        v += __shfl_xor(v, 1);
        v += __shfl_xor(v, 2);
        v += __shfl_xor(v, 4);
        v += __shfl_xor(v, 8);
        if (kk == 0 && d < NN) atomicAdd(&gsum[batch[d]], v);
    }
}

__global__ __launch_bounds__(256) void k_final(const float* gsum, const float* gcnt,
                                               const float* b3, float* out) {
    int g = blockIdx.x * 256 + threadIdx.x;
    if (g < NG) out[g] = gsum[g] / fmaxf(gcnt[g], 1.0f) + b3[0];
}

extern "C" void kernel_launch(void* const* d_in, const int* in_sizes, int n_in,
                              void* d_out, int out_size, void* d_ws, size_t ws_size,
                              hipStream_t stream) {
    const float* x     = (const float*)d_in[0];
    const int*   src   = (const int*)d_in[1];
    const int*   dst   = src + NE;
    const int*   batch = (const int*)d_in[2];
    const float* W1 = (const float*)d_in[3];
    const float* b1 = (const float*)d_in[4];
    const float* W2 = (const float*)d_in[5];
    const float* b2 = (const float*)d_in[6];
    const float* W3 = (const float*)d_in[7];
    const float* b3 = (const float*)d_in[8];
    float* out = (float*)d_out;

    float* ws = (float*)d_ws;
    int*   bcur  = (int*)(ws + O_BCUR);
    float* gsum  = ws + O_GSUM;
    float* gcnt  = ws + O_GCNT;
    float* dinv  = ws + O_DINV;
    int*   pairs = (int*)(ws + O_PAIRS);
    float* h1s   = ws + O_H1S;
    float* h2s   = ws + O_H2S;

    k_init <<<4, 256, 0, stream>>>(bcur, gsum, gcnt, h1s, h2s);
    k_stage<<<NBUK, 256, 0, stream>>>(src, dst, bcur, pairs);
    k_deg  <<<NBUK, 256, 0, stream>>>(bcur, pairs, batch, dinv, gcnt);
    k_gemm1<<<(NN + 63) / 64, 256, 0, stream>>>(x, W1, dinv, h1s);
    k_agg1 <<<NBUK, 256, 0, stream>>>(h1s, dinv, bcur, pairs, W2, b1, h2s);
    k_agg2 <<<NBUK, 256, 0, stream>>>(h2s, dinv, bcur, pairs, b2, W3, batch, gsum);
    k_final<<<2, 256, 0, stream>>>(gsum, gcnt, b3, out);
}